// Round 1
// 102.858 us; speedup vs baseline: 1.0519x; 1.0519x over previous
//
#include <hip/hip_runtime.h>
#include <hip/hip_bf16.h>
#include <math.h>

#define T_LEN 512
#define H_HEADS 8
#define DK 64
#define LR 128      // L_TABLES * R = 8 * 16
#define NTOT 32     // M*B*H

typedef __attribute__((ext_vector_type(8))) short bf16x8;   // MFMA A/B frag (8 bf16)
typedef __attribute__((ext_vector_type(4))) float f32x4;    // MFMA C/D frag

__device__ __forceinline__ float fast_tanh(float x) {
    float e = __expf(2.0f * x);
    return 1.0f - 2.0f / (1.0f + e);
}

__device__ __forceinline__ unsigned f2bf(float x) {
    union { float f; unsigned u; } v; v.f = x;
    unsigned r = v.u + 0x7FFF + ((v.u >> 16) & 1);   // RNE
    return r >> 16;
}

__device__ __forceinline__ float bflo(unsigned u) {
    union { unsigned u; float f; } v; v.u = u << 16; return v.f;
}
__device__ __forceinline__ float bfhi(unsigned u) {
    union { unsigned u; float f; } v; v.u = u & 0xFFFF0000u; return v.f;
}

// K1: per (n, 32-t tile, side): MFMA projection -> tanh -> per-table softmax.
// SIDE-SPLIT vs previous version: 1024 blocks (was 512), each does only the K
// side or the Q side -> half the serial work per block, 4 blocks/CU (was 2).
// side 0 (K): writes pKB [n][lr][t], pKt [n][t][lr], Spart.
// side 1 (Q): writes pQB [n][lr][t], VBT [n][d][t].
// Block decode bx = u*32 + n so all blocks of one n share XCD n%8.
__global__ __launch_bounds__(256) void k_probs(
    const float* __restrict__ Khf, const float* __restrict__ Qhf,
    const float* __restrict__ Vhf,
    const float* __restrict__ planesT, const float* __restrict__ protosT,
    unsigned short* __restrict__ pKB, unsigned short* __restrict__ pKt,
    unsigned short* __restrict__ pQB, unsigned short* __restrict__ VBT,
    float* __restrict__ Spart)
{
    __shared__ __align__(16) unsigned char smraw[39040];   // 38.1 KB
    short* Psh    = (short*)smraw;                 // [32][72] bf16 planes^T
    float* protos = (float*)(smraw + 4608);        // [4][16]
    short* Xsh    = (short*)(smraw + 4864);        // [32][72] bf16 (K or Q rows)
    float* xt     = (float*)(smraw + 9472);        // [32][33] tanh'd proj
    float* pbuf   = (float*)(smraw + 13696);       // [128][33]
    float* vb     = (float*)(smraw + 30592);       // [64][33] (Q-side V transpose)

    const int bx = blockIdx.x;
    const int n  = bx & 31;               // XCD = n % 8 under round-robin
    const int u  = bx >> 5;               // 0..31
    const int tile = u >> 1;              // 0..15
    const int side = u & 1;               // 0 = K, 1 = Q
    const int t0 = tile * 32;
    const int g  = n >> 3, h = n & 7;
    const int tid = threadIdx.x;
    const int wv = tid >> 6, lane = tid & 63, m16 = lane & 15, q = lane >> 4;

    // ---- stage planes^T (bf16 transpose) + protos + X rows (this side only) ----
    {
        int d = tid >> 2, jb = (tid & 3) * 8;      // 64 d x 4 j-groups
        float4 a = *(const float4*)(planesT + d * 32 + jb);
        float4 b = *(const float4*)(planesT + d * 32 + jb + 4);
        float pv[8] = {a.x, a.y, a.z, a.w, b.x, b.y, b.z, b.w};
#pragma unroll
        for (int i = 0; i < 8; ++i)
            Psh[(jb + i) * 72 + d] = (short)f2bf(pv[i]);
    }
    if (tid < 64) protos[tid] = protosT[tid];
    {
        int row = tid >> 3, seg = tid & 7;         // 256 = 32 rows x 8 segs
        const float* src = (side ? Qhf : Khf) +
            ((long)(g * T_LEN + t0 + row) * H_HEADS + h) * DK + seg * 8;
        float4 a = *(const float4*)src;
        float4 b = *(const float4*)(src + 4);
        uint4 uu;
        uu.x = f2bf(a.x) | (f2bf(a.y) << 16);
        uu.y = f2bf(a.z) | (f2bf(a.w) << 16);
        uu.z = f2bf(b.x) | (f2bf(b.y) << 16);
        uu.w = f2bf(b.z) | (f2bf(b.w) << 16);
        *(uint4*)(Xsh + row * 72 + seg * 8) = uu;
    }
    __syncthreads();

    // ---- MFMA projection: [32 rows][32 j], K=64 (2 steps), wave=(nb,mb) ----
    {
        const int mb = wv & 1, nb = wv >> 1;
        f32x4 s = (f32x4){0.f, 0.f, 0.f, 0.f};
#pragma unroll
        for (int ks = 0; ks < 2; ++ks) {
            bf16x8 af = *(const bf16x8*)(Xsh + (mb * 16 + m16) * 72 + ks * 32 + q * 8);
            bf16x8 bf = *(const bf16x8*)(Psh + (nb * 16 + m16) * 72 + ks * 32 + q * 8);
            s = __builtin_amdgcn_mfma_f32_16x16x32_bf16(af, bf, s, 0, 0, 0);
        }
        // C layout: row = q*4+p (within band), col = m16 -> xt[t2][j]
#pragma unroll
        for (int p = 0; p < 4; ++p)
            xt[(mb * 16 + q * 4 + p) * 33 + nb * 16 + m16] =
                fast_tanh(s[p]) * 0.125f;
    }
    __syncthreads();

    // ---- per-table softmax over 16 corners (|logit| <= 0.5) ----
    const int r = tid & 15, l = (tid >> 4) & 7, thi = tid >> 7;   // thi 0/1
    {
        float p0 = protos[r], p1 = protos[16 + r], p2 = protos[32 + r], p3 = protos[48 + r];
#pragma unroll 4
        for (int w = 0; w < 16; ++w) {
            int tl = w * 2 + thi;                 // 0..31
            const float* x = xt + tl * 33 + l * 4;
            float logit = x[0] * p0 + x[1] * p1 + x[2] * p2 + x[3] * p3;
            float e = __expf(logit);
            float s = e;
            s += __shfl_xor(s, 1, 16);
            s += __shfl_xor(s, 2, 16);
            s += __shfl_xor(s, 4, 16);
            s += __shfl_xor(s, 8, 16);
            pbuf[(l * 16 + r) * 33 + tl] = e / s;
        }
    }
    // Q-side: stage V into vb (separate region, covered by the barrier below)
    if (side) {
#pragma unroll
        for (int it = 0; it < 2; ++it) {
            int fid = it * 256 + tid;             // 512 = 32 t x 16 c4
            int t = fid >> 4, c4 = fid & 15;
            float4 v = *(const float4*)(Vhf + ((size_t)(g * T_LEN + t0 + t) * H_HEADS + h) * DK + c4 * 4);
            vb[(c4 * 4 + 0) * 33 + t] = v.x;
            vb[(c4 * 4 + 1) * 33 + t] = v.y;
            vb[(c4 * 4 + 2) * 33 + t] = v.z;
            vb[(c4 * 4 + 3) * 33 + t] = v.w;
        }
    }
    __syncthreads();

    if (side == 0) {
        // bf16 pack: pbuf [128 lr][32 t] -> pKB[n][lr][t0..t0+32)
        unsigned* dst = (unsigned*)pKB;
#pragma unroll
        for (int it = 0; it < 8; ++it) {
            int fid = it * 256 + tid;             // 2048 = 128 lr x 16 dwords
            int lr = fid >> 4, tp2 = fid & 15;
            unsigned u0 = f2bf(pbuf[lr * 33 + tp2 * 2]);
            unsigned u1 = f2bf(pbuf[lr * 33 + tp2 * 2 + 1]);
            dst[(size_t)(n * LR + lr) * 256 + tile * 16 + tp2] = u0 | (u1 << 16);
        }
        // transposed pack: pbuf [lr][t] -> pKt[n][t][lr]
        unsigned* dt = (unsigned*)pKt + (size_t)n * 32768 + t0 * 64;
#pragma unroll
        for (int it = 0; it < 8; ++it) {
            int fid = it * 256 + tid;             // 2048 = 32 t x 64 lr-pairs
            int t = fid >> 6, lrp = fid & 63;
            unsigned u0 = f2bf(pbuf[(2 * lrp) * 33 + t]);
            unsigned u1 = f2bf(pbuf[(2 * lrp + 1) * 33 + t]);
            dt[t * 64 + lrp] = u0 | (u1 << 16);
        }
        // per-tile pK row sums (fp32), 256-thread parallel + width-2 shuffle
        {
            int lr = tid >> 1, hf = tid & 1;
            float s = 0.f;
            const float* row = pbuf + lr * 33 + hf * 16;
#pragma unroll
            for (int t = 0; t < 16; ++t) s += row[t];
            s += __shfl_xor(s, 1, 2);
            if (!hf) Spart[((size_t)n * 16 + tile) * 128 + lr] = s;
        }
    } else {
        // bf16 pack: pbuf -> pQB[n][lr][t0..t0+32)
        unsigned* dst = (unsigned*)pQB;
#pragma unroll
        for (int it = 0; it < 8; ++it) {
            int fid = it * 256 + tid;
            int lr = fid >> 4, tp2 = fid & 15;
            unsigned u0 = f2bf(pbuf[lr * 33 + tp2 * 2]);
            unsigned u1 = f2bf(pbuf[lr * 33 + tp2 * 2 + 1]);
            dst[(size_t)(n * LR + lr) * 256 + tile * 16 + tp2] = u0 | (u1 << 16);
        }
        // V pack: vb [64 d][32 t] fp32 -> VBT[n][d][t] bf16
        unsigned* dstv = (unsigned*)VBT + (size_t)n * 16384;
#pragma unroll
        for (int it = 0; it < 4; ++it) {
            int fid = it * 256 + tid;             // 1024 = 64 d x 16 dwords
            int d = fid >> 4, tp2 = fid & 15;
            unsigned u0 = f2bf(vb[d * 33 + tp2 * 2]);
            unsigned u1 = f2bf(vb[d * 33 + tp2 * 2 + 1]);
            dstv[d * 256 + tile * 16 + tp2] = u0 | (u1 << 16);
        }
    }
}

// K2: MFMA causal attention, 1024 thr = 4 wave-groups x 4 m-band waves.
// A-prefix from Spart + bf16 in-tile scan; qw from bf16 pQB. Chunks c == wg
// (mod 4). Ksh staged directly from pKt[n][t][lr] via b128.
// Block decode bx = rt*32 + n: the 8 rt-siblings of one n share XCD n%8 ->
// pKt/VBT/pQB reads for an n stay L2-local (~450 KB/n, 4 n per XCD).
__global__ __launch_bounds__(1024) void k_attn(
    const unsigned short* __restrict__ pKB, const unsigned short* __restrict__ pKt,
    const unsigned short* __restrict__ pQB, const unsigned short* __restrict__ VBT,
    const float* __restrict__ Spart, float* __restrict__ out)
{
    __shared__ __align__(16) short sm[71680];      // 143,360 B
    const int n = blockIdx.x & 31, rt = blockIdx.x >> 5;
    const int g = n >> 3, h = n & 7;
    const int tid = threadIdx.x;
    const int wave = tid >> 6, wg = wave >> 2, w = wave & 3;
    const int lane = tid & 63, m16 = lane & 15, q = lane >> 4;
    const int gtid = tid & 255;

    short* Ksh = sm + wg * 8704;                   // [64][136] plain padded
    short* Vsh = sm + 34816 + wg * 4608;           // [64][72]
    short* Ssh = sm + 53248 + wg * 4608;           // [64][72]
    short* Qsh = sm;                               // aliases Ksh[0] pre-loop (XOR-swizzled)

    // ---- A-prefix + qw -> Qsh (bf16, swizzled) ----
    {
        const int s8 = lane & 7;
        const int lr = wave * 8 + (lane >> 3);     // 16 waves x 8 = 128
        float bsum = 0.f;
        for (int j = 0; j < 2 * rt; ++j)           // 32-t tile sums below rt*64
            bsum += Spart[((size_t)n * 16 + j) * 128 + lr];
        uint4 ku = *(const uint4*)(pKB + ((size_t)n * LR + lr) * 512 + rt * 64 + s8 * 8);
        unsigned kuu[4] = {ku.x, ku.y, ku.z, ku.w};
        float s[8];
        s[0] = bflo(kuu[0]);        s[1] = s[0] + bfhi(kuu[0]);
        s[2] = s[1] + bflo(kuu[1]); s[3] = s[2] + bfhi(kuu[1]);
        s[4] = s[3] + bflo(kuu[2]); s[5] = s[4] + bfhi(kuu[2]);
        s[6] = s[5] + bflo(kuu[3]); s[7] = s[6] + bfhi(kuu[3]);
        float tot = s[7];
#pragma unroll
        for (int off = 1; off < 8; off <<= 1) {    // segmented scan (width 8)
            float v = __shfl_up(tot, off, 8);
            if (s8 >= off) tot += v;
        }
        float base = bsum + tot - s[7];            // exclusive prefix before lane's span
        uint4 qu = *(const uint4*)(pQB + ((size_t)n * LR + lr) * 512 + rt * 64 + s8 * 8);
        unsigned quu[4] = {qu.x, qu.y, qu.z, qu.w};
        float qf[8] = {bflo(quu[0]), bfhi(quu[0]), bflo(quu[1]), bfhi(quu[1]),
                       bflo(quu[2]), bfhi(quu[2]), bflo(quu[3]), bfhi(quu[3])};
        const int qbase = ((wave ^ s8) << 3) + (lr & 7);   // lr>>3 == wave
#pragma unroll
        for (int i = 0; i < 8; ++i)
            Qsh[(s8 * 8 + i) * 136 + qbase] = (short)f2bf(qf[i] / (base + s[i] + 1e-6f));
    }
    __syncthreads();

    bf16x8 qa[4];
    {
        const int row = w * 16 + m16, rk = row >> 3;
#pragma unroll
        for (int st = 0; st < 4; ++st)
            qa[st] = *(const bf16x8*)(Qsh + row * 136 + (((st * 4 + q) ^ rk) << 3));
    }

    const unsigned short* kt = pKt + (size_t)n * 65536;   // [t][lr]
    const unsigned short* kv = VBT + (size_t)n * 32768;   // [d][t]
    uint4 pk[4], pv[2];
    auto pref = [&](int c) {
#pragma unroll
        for (int it = 0; it < 4; ++it) {           // 1024 uint4 = 64 rows x 16 segs
            int fid = it * 256 + gtid;
            pk[it] = *(const uint4*)(kt + (size_t)(c * 64 + (fid >> 4)) * 128 + (fid & 15) * 8);
        }
#pragma unroll
        for (int it = 0; it < 2; ++it) {
            int fid = it * 256 + gtid;
            pv[it] = *(const uint4*)(kv + (size_t)(fid >> 3) * 512 + c * 64 + (fid & 7) * 8);
        }
    };

    f32x4 o[4];
    o[0] = o[1] = o[2] = o[3] = (f32x4){0.f, 0.f, 0.f, 0.f};

    if (wg <= rt) pref(wg);
    const int rounds = (rt >> 2) + 1;
    for (int r0 = 0; r0 < rounds; ++r0) {
        const int c = r0 * 4 + wg;
        const bool act = (c <= rt);
        __syncthreads();                           // prior round reads done (also Q stage)
        if (act) {
#pragma unroll
            for (int it = 0; it < 4; ++it) {
                int fid = it * 256 + gtid;
                *(uint4*)(Ksh + (fid >> 4) * 136 + (fid & 15) * 8) = pk[it];
            }
            *(uint4*)(Vsh + (gtid >> 3) * 72 + (gtid & 7) * 8) = pv[0];
            *(uint4*)(Vsh + ((gtid + 256) >> 3) * 72 + (gtid & 7) * 8) = pv[1];
        }
        __syncthreads();
        if (c + 4 <= rt) pref(c + 4);
        if (act) {
            f32x4 s[4];
            s[0] = s[1] = s[2] = s[3] = (f32x4){0.f, 0.f, 0.f, 0.f};
#pragma unroll
            for (int st = 0; st < 4; ++st)
#pragma unroll
                for (int nb = 0; nb < 4; ++nb) {
                    bf16x8 b = *(const bf16x8*)(Ksh + (nb * 16 + m16) * 136 + st * 32 + q * 8);
                    s[nb] = __builtin_amdgcn_mfma_f32_16x16x32_bf16(qa[st], b, s[nb], 0, 0, 0);
                }
            if (c == rt) {                         // causal: keep j <= i
#pragma unroll
                for (int nb = 0; nb < 4; ++nb)
#pragma unroll
                    for (int p = 0; p < 4; ++p)
                        if (nb * 16 + m16 > w * 16 + q * 4 + p) s[nb][p] = 0.f;
            }
#pragma unroll
            for (int nb = 0; nb < 4; ++nb)
#pragma unroll
                for (int p = 0; p < 4; ++p) {
                    union { float f; unsigned u; } cv; cv.f = s[nb][p];
                    Ssh[(w * 16 + q * 4 + p) * 72 + nb * 16 + m16] =
                        (short)((cv.u + 0x8000u) >> 16);
                }
#pragma unroll
            for (int st = 0; st < 2; ++st) {
                bf16x8 a = *(const bf16x8*)(Ssh + (w * 16 + m16) * 72 + st * 32 + q * 8);
#pragma unroll
                for (int nb = 0; nb < 4; ++nb) {
                    bf16x8 b = *(const bf16x8*)(Vsh + (nb * 16 + m16) * 72 + st * 32 + q * 8);
                    o[nb] = __builtin_amdgcn_mfma_f32_16x16x32_bf16(a, b, o[nb], 0, 0, 0);
                }
            }
        }
    }

    // combine 4 wave-group partials via LDS (K/Q regions dead)
    __syncthreads();
    float* Obuf = (float*)sm;                      // 3 x [64][68] f32
    if (wg) {
        float* ob = Obuf + (wg - 1) * 4352;
#pragma unroll
        for (int nb = 0; nb < 4; ++nb)
#pragma unroll
            for (int p = 0; p < 4; ++p)
                ob[(w * 16 + q * 4 + p) * 68 + nb * 16 + m16] = o[nb][p];
    }
    __syncthreads();
    if (wg == 0) {
        float* dst = out + ((size_t)(g * T_LEN + rt * 64 + w * 16 + q * 4) * H_HEADS + h) * DK;
#pragma unroll
        for (int p = 0; p < 4; ++p)
#pragma unroll
            for (int nb = 0; nb < 4; ++nb) {
                int idx = (w * 16 + q * 4 + p) * 68 + nb * 16 + m16;
                dst[p * (H_HEADS * DK) + nb * 16 + m16] =
                    o[nb][p] + Obuf[idx] + Obuf[4352 + idx] + Obuf[8704 + idx];
            }
    }
}

extern "C" void kernel_launch(void* const* d_in, const int* in_sizes, int n_in,
                              void* d_out, int out_size, void* d_ws, size_t ws_size,
                              hipStream_t stream) {
    const float* Khf     = (const float*)d_in[0];
    const float* Vhf     = (const float*)d_in[1];
    const float* Qhf     = (const float*)d_in[2];
    const float* planesT = (const float*)d_in[3];
    const float* protosT = (const float*)d_in[4];
    float* outp = (float*)d_out;

    const size_t NE = (size_t)NTOT * LR * T_LEN;        // 2,097,152
    unsigned short* pKB = (unsigned short*)d_ws;        // bf16 [n][lr][t]
    unsigned short* pKt = pKB + NE;                     // bf16 [n][t][lr]
    unsigned short* pQB = pKt + NE;                     // bf16 [n][lr][t]
    unsigned short* VBT = pQB + NE;                     // bf16 [n][d][t]
    float* Spart = (float*)(VBT + (size_t)NTOT * DK * T_LEN);  // fp32 [n][16][128]

    k_probs<<<dim3(1024), dim3(256), 0, stream>>>(
        Khf, Qhf, Vhf, planesT, protosT, pKB, pKt, pQB, VBT, Spart);
    k_attn<<<dim3(256), dim3(1024), 0, stream>>>(pKB, pKt, pQB, VBT, Spart, outp);
}

// Round 2
// 96.490 us; speedup vs baseline: 1.1213x; 1.0660x over previous
//
#include <hip/hip_runtime.h>
#include <hip/hip_bf16.h>
#include <math.h>

#define T_LEN 512
#define H_HEADS 8
#define DK 64
#define LR 128      // L_TABLES * R = 8 * 16
#define NTOT 32     // M*B*H

typedef __attribute__((ext_vector_type(8))) short bf16x8;   // MFMA A/B frag (8 bf16)
typedef __attribute__((ext_vector_type(4))) float f32x4;    // MFMA C/D frag

__device__ __forceinline__ float fast_tanh(float x) {
    float e = __expf(2.0f * x);
    return 1.0f - 2.0f / (1.0f + e);
}

__device__ __forceinline__ unsigned f2bf(float x) {
    union { float f; unsigned u; } v; v.f = x;
    unsigned r = v.u + 0x7FFF + ((v.u >> 16) & 1);   // RNE
    return r >> 16;
}

__device__ __forceinline__ float bflo(unsigned u) {
    union { unsigned u; float f; } v; v.u = u << 16; return v.f;
}
__device__ __forceinline__ float bfhi(unsigned u) {
    union { unsigned u; float f; } v; v.u = u & 0xFFFF0000u; return v.f;
}

// K1: per (n, 32-t tile, side): MFMA projection -> tanh -> SEPARABLE softmax.
// Softmax over the 16 hypercube corners factorizes exactly:
//   prob(r) = prod_k [ bit_k(r) ? sigmoid(2 s_k) : 1 - sigmoid(2 s_k) ]
// (corners are all sign combos), so no exp-per-corner, no shuffle reduce,
// no normalization divide, and no protos table.
// side 0 (K): writes pKB [n][lr][t], pKt [n][t][lr] (direct from regs), Spart.
// side 1 (Q): writes pQB [n][lr][t], VBT [n][d][t].
// Block decode bx = u*32 + n so all blocks of one n share XCD n%8.
__global__ __launch_bounds__(256) void k_probs(
    const float* __restrict__ Khf, const float* __restrict__ Qhf,
    const float* __restrict__ Vhf, const float* __restrict__ planesT,
    unsigned short* __restrict__ pKB, unsigned short* __restrict__ pKt,
    unsigned short* __restrict__ pQB, unsigned short* __restrict__ VBT,
    float* __restrict__ Spart)
{
    __shared__ __align__(16) unsigned char smraw[39040];   // 38.1 KB
    short* Psh    = (short*)smraw;                 // [32][72] bf16 planes^T
    short* Xsh    = (short*)(smraw + 4864);        // [32][72] bf16 (K or Q rows)
    float* xt     = (float*)(smraw + 9472);        // [32][33] tanh'd proj (s_k)
    float* pbuf   = (float*)(smraw + 13696);       // [128][33]
    float* vb     = (float*)(smraw + 30592);       // [64][33] (Q-side V transpose)

    const int bx = blockIdx.x;
    const int n  = bx & 31;               // XCD = n % 8 under round-robin
    const int u  = bx >> 5;               // 0..31
    const int tile = u >> 1;              // 0..15
    const int side = u & 1;               // 0 = K, 1 = Q
    const int t0 = tile * 32;
    const int g  = n >> 3, h = n & 7;
    const int tid = threadIdx.x;
    const int wv = tid >> 6, lane = tid & 63, m16 = lane & 15, q = lane >> 4;

    // ---- stage planes^T (bf16 transpose) + X rows (this side only) ----
    {
        int d = tid >> 2, jb = (tid & 3) * 8;      // 64 d x 4 j-groups
        float4 a = *(const float4*)(planesT + d * 32 + jb);
        float4 b = *(const float4*)(planesT + d * 32 + jb + 4);
        float pv[8] = {a.x, a.y, a.z, a.w, b.x, b.y, b.z, b.w};
#pragma unroll
        for (int i = 0; i < 8; ++i)
            Psh[(jb + i) * 72 + d] = (short)f2bf(pv[i]);
    }
    {
        int row = tid >> 3, seg = tid & 7;         // 256 = 32 rows x 8 segs
        const float* src = (side ? Qhf : Khf) +
            ((long)(g * T_LEN + t0 + row) * H_HEADS + h) * DK + seg * 8;
        float4 a = *(const float4*)src;
        float4 b = *(const float4*)(src + 4);
        uint4 uu;
        uu.x = f2bf(a.x) | (f2bf(a.y) << 16);
        uu.y = f2bf(a.z) | (f2bf(a.w) << 16);
        uu.z = f2bf(b.x) | (f2bf(b.y) << 16);
        uu.w = f2bf(b.z) | (f2bf(b.w) << 16);
        *(uint4*)(Xsh + row * 72 + seg * 8) = uu;
    }
    __syncthreads();

    // ---- MFMA projection: [32 rows][32 j], K=64 (2 steps), wave=(nb,mb) ----
    {
        const int mb = wv & 1, nb = wv >> 1;
        f32x4 s = (f32x4){0.f, 0.f, 0.f, 0.f};
#pragma unroll
        for (int ks = 0; ks < 2; ++ks) {
            bf16x8 af = *(const bf16x8*)(Xsh + (mb * 16 + m16) * 72 + ks * 32 + q * 8);
            bf16x8 bf = *(const bf16x8*)(Psh + (nb * 16 + m16) * 72 + ks * 32 + q * 8);
            s = __builtin_amdgcn_mfma_f32_16x16x32_bf16(af, bf, s, 0, 0, 0);
        }
        // C layout: row = q*4+p (within band), col = m16 -> xt[t2][j]
#pragma unroll
        for (int p = 0; p < 4; ++p)
            xt[(mb * 16 + q * 4 + p) * 33 + nb * 16 + m16] =
                fast_tanh(s[p]) * 0.125f;
    }
    __syncthreads();

    // ---- separable softmax: thread owns (t, table l), all 16 corners ----
    {
        const int tl = tid & 31, l = tid >> 5;     // 32 t x 8 l
        const float* x = xt + tl * 33 + l * 4;
        float P[4], M[4];
#pragma unroll
        for (int k = 0; k < 4; ++k) {
            float e = __expf(-2.0f * x[k]);        // sigmoid(2 s_k)
            float inv = 1.0f / (1.0f + e);
            P[k] = inv; M[k] = e * inv;            // P + M = 1 exactly enough
        }
        // corner r bits (b3 b2 b1 b0) correspond to k = (0,1,2,3); +1 iff bit set
        float ab[4] = {M[0]*M[1], M[0]*P[1], P[0]*M[1], P[0]*P[1]};
        float cd[4] = {M[2]*M[3], M[2]*P[3], P[2]*M[3], P[2]*P[3]};
        float* pb = pbuf + (l * 16) * 33 + tl;
        unsigned w0x, w0y, w0z, w0w, w1x, w1y, w1z, w1w;
        float pr[16];
#pragma unroll
        for (int r = 0; r < 16; ++r) {
            pr[r] = ab[r >> 2] * cd[r & 3];
            pb[r * 33] = pr[r];
        }
        if (side == 0) {
            w0x = f2bf(pr[0])  | (f2bf(pr[1])  << 16);
            w0y = f2bf(pr[2])  | (f2bf(pr[3])  << 16);
            w0z = f2bf(pr[4])  | (f2bf(pr[5])  << 16);
            w0w = f2bf(pr[6])  | (f2bf(pr[7])  << 16);
            w1x = f2bf(pr[8])  | (f2bf(pr[9])  << 16);
            w1y = f2bf(pr[10]) | (f2bf(pr[11]) << 16);
            w1z = f2bf(pr[12]) | (f2bf(pr[13]) << 16);
            w1w = f2bf(pr[14]) | (f2bf(pr[15]) << 16);
            unsigned short* dt = pKt + (size_t)n * 65536 + (size_t)(t0 + tl) * 128 + l * 16;
            uint4 a; a.x = w0x; a.y = w0y; a.z = w0z; a.w = w0w;
            uint4 b; b.x = w1x; b.y = w1y; b.z = w1z; b.w = w1w;
            *(uint4*)dt       = a;
            *(uint4*)(dt + 8) = b;
        }
    }
    // Q-side: stage V into vb (separate region, covered by the barrier below)
    if (side) {
#pragma unroll
        for (int it = 0; it < 2; ++it) {
            int fid = it * 256 + tid;             // 512 = 32 t x 16 c4
            int t = fid >> 4, c4 = fid & 15;
            float4 v = *(const float4*)(Vhf + ((size_t)(g * T_LEN + t0 + t) * H_HEADS + h) * DK + c4 * 4);
            vb[(c4 * 4 + 0) * 33 + t] = v.x;
            vb[(c4 * 4 + 1) * 33 + t] = v.y;
            vb[(c4 * 4 + 2) * 33 + t] = v.z;
            vb[(c4 * 4 + 3) * 33 + t] = v.w;
        }
    }
    __syncthreads();

    if (side == 0) {
        // bf16 pack: pbuf [128 lr][32 t] -> pKB[n][lr][t0..t0+32)
        unsigned* dst = (unsigned*)pKB;
#pragma unroll
        for (int it = 0; it < 8; ++it) {
            int fid = it * 256 + tid;             // 2048 = 128 lr x 16 dwords
            int lr = fid >> 4, tp2 = fid & 15;
            unsigned u0 = f2bf(pbuf[lr * 33 + tp2 * 2]);
            unsigned u1 = f2bf(pbuf[lr * 33 + tp2 * 2 + 1]);
            dst[(size_t)(n * LR + lr) * 256 + tile * 16 + tp2] = u0 | (u1 << 16);
        }
        // per-tile pK row sums (fp32), 256-thread parallel + width-2 shuffle
        {
            int lr = tid >> 1, hf = tid & 1;
            float s = 0.f;
            const float* row = pbuf + lr * 33 + hf * 16;
#pragma unroll
            for (int t = 0; t < 16; ++t) s += row[t];
            s += __shfl_xor(s, 1, 2);
            if (!hf) Spart[((size_t)n * 16 + tile) * 128 + lr] = s;
        }
    } else {
        // bf16 pack: pbuf -> pQB[n][lr][t0..t0+32)
        unsigned* dst = (unsigned*)pQB;
#pragma unroll
        for (int it = 0; it < 8; ++it) {
            int fid = it * 256 + tid;
            int lr = fid >> 4, tp2 = fid & 15;
            unsigned u0 = f2bf(pbuf[lr * 33 + tp2 * 2]);
            unsigned u1 = f2bf(pbuf[lr * 33 + tp2 * 2 + 1]);
            dst[(size_t)(n * LR + lr) * 256 + tile * 16 + tp2] = u0 | (u1 << 16);
        }
        // V pack: vb [64 d][32 t] fp32 -> VBT[n][d][t] bf16
        unsigned* dstv = (unsigned*)VBT + (size_t)n * 16384;
#pragma unroll
        for (int it = 0; it < 4; ++it) {
            int fid = it * 256 + tid;             // 1024 = 64 d x 16 dwords
            int d = fid >> 4, tp2 = fid & 15;
            unsigned u0 = f2bf(vb[d * 33 + tp2 * 2]);
            unsigned u1 = f2bf(vb[d * 33 + tp2 * 2 + 1]);
            dstv[d * 256 + tile * 16 + tp2] = u0 | (u1 << 16);
        }
    }
}

// K2: MFMA causal attention, 1024 thr = 4 wave-groups x 4 m-band waves.
// A-prefix from Spart + bf16 in-tile scan; qw from bf16 pQB. Chunks c == wg
// (mod 4). Ksh staged directly from pKt[n][t][lr] via b128.
// Block decode bx = rt*32 + n: the 8 rt-siblings of one n share XCD n%8 ->
// pKt/VBT/pQB reads for an n stay L2-local (~450 KB/n, 4 n per XCD).
__global__ __launch_bounds__(1024) void k_attn(
    const unsigned short* __restrict__ pKB, const unsigned short* __restrict__ pKt,
    const unsigned short* __restrict__ pQB, const unsigned short* __restrict__ VBT,
    const float* __restrict__ Spart, float* __restrict__ out)
{
    __shared__ __align__(16) short sm[71680];      // 143,360 B
    const int n = blockIdx.x & 31, rt = blockIdx.x >> 5;
    const int g = n >> 3, h = n & 7;
    const int tid = threadIdx.x;
    const int wave = tid >> 6, wg = wave >> 2, w = wave & 3;
    const int lane = tid & 63, m16 = lane & 15, q = lane >> 4;
    const int gtid = tid & 255;

    short* Ksh = sm + wg * 8704;                   // [64][136] plain padded
    short* Vsh = sm + 34816 + wg * 4608;           // [64][72]
    short* Ssh = sm + 53248 + wg * 4608;           // [64][72]
    short* Qsh = sm;                               // aliases Ksh[0] pre-loop (XOR-swizzled)

    // ---- A-prefix + qw -> Qsh (bf16, swizzled) ----
    {
        const int s8 = lane & 7;
        const int lr = wave * 8 + (lane >> 3);     // 16 waves x 8 = 128
        float bsum = 0.f;
        for (int j = 0; j < 2 * rt; ++j)           // 32-t tile sums below rt*64
            bsum += Spart[((size_t)n * 16 + j) * 128 + lr];
        uint4 ku = *(const uint4*)(pKB + ((size_t)n * LR + lr) * 512 + rt * 64 + s8 * 8);
        unsigned kuu[4] = {ku.x, ku.y, ku.z, ku.w};
        float s[8];
        s[0] = bflo(kuu[0]);        s[1] = s[0] + bfhi(kuu[0]);
        s[2] = s[1] + bflo(kuu[1]); s[3] = s[2] + bfhi(kuu[1]);
        s[4] = s[3] + bflo(kuu[2]); s[5] = s[4] + bfhi(kuu[2]);
        s[6] = s[5] + bflo(kuu[3]); s[7] = s[6] + bfhi(kuu[3]);
        float tot = s[7];
#pragma unroll
        for (int off = 1; off < 8; off <<= 1) {    // segmented scan (width 8)
            float v = __shfl_up(tot, off, 8);
            if (s8 >= off) tot += v;
        }
        float base = bsum + tot - s[7];            // exclusive prefix before lane's span
        uint4 qu = *(const uint4*)(pQB + ((size_t)n * LR + lr) * 512 + rt * 64 + s8 * 8);
        unsigned quu[4] = {qu.x, qu.y, qu.z, qu.w};
        float qf[8] = {bflo(quu[0]), bfhi(quu[0]), bflo(quu[1]), bfhi(quu[1]),
                       bflo(quu[2]), bfhi(quu[2]), bflo(quu[3]), bfhi(quu[3])};
        const int qbase = ((wave ^ s8) << 3) + (lr & 7);   // lr>>3 == wave
#pragma unroll
        for (int i = 0; i < 8; ++i)
            Qsh[(s8 * 8 + i) * 136 + qbase] = (short)f2bf(qf[i] / (base + s[i] + 1e-6f));
    }
    __syncthreads();

    bf16x8 qa[4];
    {
        const int row = w * 16 + m16, rk = row >> 3;
#pragma unroll
        for (int st = 0; st < 4; ++st)
            qa[st] = *(const bf16x8*)(Qsh + row * 136 + (((st * 4 + q) ^ rk) << 3));
    }

    const unsigned short* kt = pKt + (size_t)n * 65536;   // [t][lr]
    const unsigned short* kv = VBT + (size_t)n * 32768;   // [d][t]
    uint4 pk[4], pv[2];
    auto pref = [&](int c) {
#pragma unroll
        for (int it = 0; it < 4; ++it) {           // 1024 uint4 = 64 rows x 16 segs
            int fid = it * 256 + gtid;
            pk[it] = *(const uint4*)(kt + (size_t)(c * 64 + (fid >> 4)) * 128 + (fid & 15) * 8);
        }
#pragma unroll
        for (int it = 0; it < 2; ++it) {
            int fid = it * 256 + gtid;
            pv[it] = *(const uint4*)(kv + (size_t)(fid >> 3) * 512 + c * 64 + (fid & 7) * 8);
        }
    };

    f32x4 o[4];
    o[0] = o[1] = o[2] = o[3] = (f32x4){0.f, 0.f, 0.f, 0.f};

    if (wg <= rt) pref(wg);
    const int rounds = (rt >> 2) + 1;
    for (int r0 = 0; r0 < rounds; ++r0) {
        const int c = r0 * 4 + wg;
        const bool act = (c <= rt);
        __syncthreads();                           // prior round reads done (also Q stage)
        if (act) {
#pragma unroll
            for (int it = 0; it < 4; ++it) {
                int fid = it * 256 + gtid;
                *(uint4*)(Ksh + (fid >> 4) * 136 + (fid & 15) * 8) = pk[it];
            }
            *(uint4*)(Vsh + (gtid >> 3) * 72 + (gtid & 7) * 8) = pv[0];
            *(uint4*)(Vsh + ((gtid + 256) >> 3) * 72 + (gtid & 7) * 8) = pv[1];
        }
        __syncthreads();
        if (c + 4 <= rt) pref(c + 4);
        if (act) {
            f32x4 s[4];
            s[0] = s[1] = s[2] = s[3] = (f32x4){0.f, 0.f, 0.f, 0.f};
#pragma unroll
            for (int st = 0; st < 4; ++st)
#pragma unroll
                for (int nb = 0; nb < 4; ++nb) {
                    bf16x8 b = *(const bf16x8*)(Ksh + (nb * 16 + m16) * 136 + st * 32 + q * 8);
                    s[nb] = __builtin_amdgcn_mfma_f32_16x16x32_bf16(qa[st], b, s[nb], 0, 0, 0);
                }
            if (c == rt) {                         // causal: keep j <= i
#pragma unroll
                for (int nb = 0; nb < 4; ++nb)
#pragma unroll
                    for (int p = 0; p < 4; ++p)
                        if (nb * 16 + m16 > w * 16 + q * 4 + p) s[nb][p] = 0.f;
            }
#pragma unroll
            for (int nb = 0; nb < 4; ++nb)
#pragma unroll
                for (int p = 0; p < 4; ++p) {
                    union { float f; unsigned u; } cv; cv.f = s[nb][p];
                    Ssh[(w * 16 + q * 4 + p) * 72 + nb * 16 + m16] =
                        (short)((cv.u + 0x8000u) >> 16);
                }
#pragma unroll
            for (int st = 0; st < 2; ++st) {
                bf16x8 a = *(const bf16x8*)(Ssh + (w * 16 + m16) * 72 + st * 32 + q * 8);
#pragma unroll
                for (int nb = 0; nb < 4; ++nb) {
                    bf16x8 b = *(const bf16x8*)(Vsh + (nb * 16 + m16) * 72 + st * 32 + q * 8);
                    o[nb] = __builtin_amdgcn_mfma_f32_16x16x32_bf16(a, b, o[nb], 0, 0, 0);
                }
            }
        }
    }

    // combine 4 wave-group partials via LDS (K/Q regions dead)
    __syncthreads();
    float* Obuf = (float*)sm;                      // 3 x [64][68] f32
    if (wg) {
        float* ob = Obuf + (wg - 1) * 4352;
#pragma unroll
        for (int nb = 0; nb < 4; ++nb)
#pragma unroll
            for (int p = 0; p < 4; ++p)
                ob[(w * 16 + q * 4 + p) * 68 + nb * 16 + m16] = o[nb][p];
    }
    __syncthreads();
    if (wg == 0) {
        float* dst = out + ((size_t)(g * T_LEN + rt * 64 + w * 16 + q * 4) * H_HEADS + h) * DK;
#pragma unroll
        for (int p = 0; p < 4; ++p)
#pragma unroll
            for (int nb = 0; nb < 4; ++nb) {
                int idx = (w * 16 + q * 4 + p) * 68 + nb * 16 + m16;
                dst[p * (H_HEADS * DK) + nb * 16 + m16] =
                    o[nb][p] + Obuf[idx] + Obuf[4352 + idx] + Obuf[8704 + idx];
            }
    }
}

extern "C" void kernel_launch(void* const* d_in, const int* in_sizes, int n_in,
                              void* d_out, int out_size, void* d_ws, size_t ws_size,
                              hipStream_t stream) {
    const float* Khf     = (const float*)d_in[0];
    const float* Vhf     = (const float*)d_in[1];
    const float* Qhf     = (const float*)d_in[2];
    const float* planesT = (const float*)d_in[3];
    float* outp = (float*)d_out;

    const size_t NE = (size_t)NTOT * LR * T_LEN;        // 2,097,152
    unsigned short* pKB = (unsigned short*)d_ws;        // bf16 [n][lr][t]
    unsigned short* pKt = pKB + NE;                     // bf16 [n][t][lr]
    unsigned short* pQB = pKt + NE;                     // bf16 [n][lr][t]
    unsigned short* VBT = pQB + NE;                     // bf16 [n][d][t]
    float* Spart = (float*)(VBT + (size_t)NTOT * DK * T_LEN);  // fp32 [n][16][128]

    k_probs<<<dim3(1024), dim3(256), 0, stream>>>(
        Khf, Qhf, Vhf, planesT, pKB, pKt, pQB, VBT, Spart);
    k_attn<<<dim3(256), dim3(1024), 0, stream>>>(pKB, pKt, pQB, VBT, Spart, outp);
}